// Round 1
// baseline (308.539 us; speedup 1.0000x reference)
//
#include <hip/hip_runtime.h>

#define NN 40000
#define NE 320000
#define C 256
#define KORD 5
#define KT 1280          // fused K = 5 * 256

typedef __attribute__((ext_vector_type(8))) short short8;   // 8 x bf16 (4 VGPR)
typedef __attribute__((ext_vector_type(4))) float floatx4;  // 4 x f32
typedef unsigned short bf16_t;

__device__ __forceinline__ bf16_t f2bf(float f) {
    union { float f; unsigned u; } v; v.f = f;
    unsigned r = v.u + 0x7fffu + ((v.u >> 16) & 1u);  // RTNE
    return (bf16_t)(r >> 16);
}
__device__ __forceinline__ float bf2f(bf16_t h) {
    union { unsigned u; float f; } v; v.u = ((unsigned)h) << 16;
    return v.f;
}

#define GLL16(gsrc, ldst)                                                        \
    __builtin_amdgcn_global_load_lds(                                            \
        (const __attribute__((address_space(1))) void*)(gsrc),                   \
        (__attribute__((address_space(3))) void*)(ldst), 16, 0, 0)

// ---------------- graph preprocessing ----------------

__global__ void count_kernel(const int* __restrict__ ei,
                             int* __restrict__ deg_keep,
                             int* __restrict__ cnt_all) {
    int e = blockIdx.x * 256 + threadIdx.x;
    if (e >= NE) return;
    int r = ei[e];
    int c = ei[NE + e];
    atomicAdd(&cnt_all[r], 1);
    if (r != c) atomicAdd(&deg_keep[r], 1);
}

__global__ void dis_kernel(const int* __restrict__ deg, float* __restrict__ dis) {
    int n = blockIdx.x * 256 + threadIdx.x;
    if (n >= NN) return;
    int d = deg[n];
    dis[n] = (d > 0) ? rsqrtf((float)d) : 0.0f;
}

__global__ void scan1_kernel(const int* __restrict__ cnt,
                             int* __restrict__ incl,
                             int* __restrict__ bsum) {
    __shared__ int s[256];
    int t = threadIdx.x;
    int idx = blockIdx.x * 256 + t;
    int v = (idx < NN) ? cnt[idx] : 0;
    s[t] = v;
    __syncthreads();
    for (int off = 1; off < 256; off <<= 1) {
        int add = (t >= off) ? s[t - off] : 0;
        __syncthreads();
        s[t] += add;
        __syncthreads();
    }
    if (idx < NN) incl[idx] = s[t];
    if (t == 255) bsum[blockIdx.x] = s[255];
}

__global__ void scan2_kernel(int* __restrict__ bsum, int nb) {
    __shared__ int s[256];
    int t = threadIdx.x;
    int v = (t < nb) ? bsum[t] : 0;
    s[t] = v;
    __syncthreads();
    for (int off = 1; off < 256; off <<= 1) {
        int add = (t >= off) ? s[t - off] : 0;
        __syncthreads();
        s[t] += add;
        __syncthreads();
    }
    if (t < nb) bsum[t] = s[t] - v;   // exclusive
}

__global__ void scan3_kernel(const int* __restrict__ cnt,
                             const int* __restrict__ incl,
                             const int* __restrict__ bexcl,
                             int* __restrict__ row_ptr,
                             int* __restrict__ cursor) {
    int idx = blockIdx.x * 256 + threadIdx.x;
    if (idx == 0) row_ptr[NN] = NE;
    if (idx >= NN) return;
    int rp = incl[idx] - cnt[idx] + bexcl[blockIdx.x];
    row_ptr[idx] = rp;
    cursor[idx]  = rp;
}

__global__ void fill_kernel(const int* __restrict__ ei,
                            const float* __restrict__ ew,
                            const float* __restrict__ dis,
                            int* __restrict__ cursor,
                            int* __restrict__ csr_col,
                            float* __restrict__ csr_val) {
    int e = blockIdx.x * 256 + threadIdx.x;
    if (e >= NE) return;
    int r = ei[e];
    int c = ei[NE + e];
    int pos = atomicAdd(&cursor[r], 1);
    float w = (r != c) ? ew[e] : 0.0f;     // removed self-loops -> weight 0
    csr_col[pos] = c;
    csr_val[pos] = -dis[r] * w * dis[c];
}

// convert x (fp32 [NN][256]) into bf16 A-chunk 0 of [NN][KT]
__global__ void convx_kernel(const float* __restrict__ x, bf16_t* __restrict__ abf) {
    int i = blockIdx.x * 256 + threadIdx.x;
    if (i >= NN * 64) return;
    int n = i >> 6, cg = i & 63;
    float4 f = *(const float4*)&x[(size_t)n * C + cg * 4];
    ushort4 h;
    h.x = f2bf(f.x); h.y = f2bf(f.y); h.z = f2bf(f.z); h.w = f2bf(f.w);
    *(ushort4*)&abf[(size_t)n * KT + cg * 4] = h;
}

// transpose+convert W[5][256][256] -> WT[n(256)][kt(1280)] bf16
__global__ void wt_kernel(const float* __restrict__ W, bf16_t* __restrict__ WT) {
    int t = blockIdx.x * 256 + threadIdx.x;
    if (t >= 256 * KT) return;
    int n = t & 255, kt = t >> 8;
    WT[(size_t)n * KT + kt] = f2bf(W[(size_t)kt * 256 + n]);
}

// ---------------- SpMM (bf16 state, unroll-8 MLP) ----------------
// outb[n][:] = bf16( alpha * sum_j val[j]*Vb[col[j]][:] - (use_sub ? subb[n][:] : 0) )
__global__ __launch_bounds__(256)
void spmm_kernel(const bf16_t* __restrict__ Vb,
                 const bf16_t* __restrict__ subb,
                 const int* __restrict__ row_ptr,
                 const int* __restrict__ csr_col,
                 const float* __restrict__ csr_val,
                 bf16_t* __restrict__ outb,
                 float alpha, int use_sub) {
    int wave = __builtin_amdgcn_readfirstlane(threadIdx.x >> 6);  // wave-uniform
    int lane = threadIdx.x & 63;
    int n = blockIdx.x * 4 + wave;          // grid is exactly NN/4 blocks
    int j0 = row_ptr[n];
    int j1 = row_ptr[n + 1];
    int cb = lane * 4;
    float a0 = 0.f, a1 = 0.f, a2 = 0.f, a3 = 0.f;
    int j = j0;
    for (; j + 8 <= j1; j += 8) {
        int cc[8]; float ww[8]; ushort4 vv[8];
#pragma unroll
        for (int u = 0; u < 8; ++u) { cc[u] = csr_col[j + u]; ww[u] = csr_val[j + u]; }
#pragma unroll
        for (int u = 0; u < 8; ++u) vv[u] = *(const ushort4*)&Vb[(size_t)cc[u] * KT + cb];
#pragma unroll
        for (int u = 0; u < 8; ++u) {
            a0 += ww[u] * bf2f(vv[u].x); a1 += ww[u] * bf2f(vv[u].y);
            a2 += ww[u] * bf2f(vv[u].z); a3 += ww[u] * bf2f(vv[u].w);
        }
    }
    for (; j + 4 <= j1; j += 4) {
        int cc[4]; float ww[4]; ushort4 vv[4];
#pragma unroll
        for (int u = 0; u < 4; ++u) { cc[u] = csr_col[j + u]; ww[u] = csr_val[j + u]; }
#pragma unroll
        for (int u = 0; u < 4; ++u) vv[u] = *(const ushort4*)&Vb[(size_t)cc[u] * KT + cb];
#pragma unroll
        for (int u = 0; u < 4; ++u) {
            a0 += ww[u] * bf2f(vv[u].x); a1 += ww[u] * bf2f(vv[u].y);
            a2 += ww[u] * bf2f(vv[u].z); a3 += ww[u] * bf2f(vv[u].w);
        }
    }
    for (; j < j1; ++j) {
        int   col = csr_col[j];
        float w   = csr_val[j];
        ushort4 v = *(const ushort4*)&Vb[(size_t)col * KT + cb];
        a0 += w * bf2f(v.x); a1 += w * bf2f(v.y);
        a2 += w * bf2f(v.z); a3 += w * bf2f(v.w);
    }
    float r0, r1, r2, r3;
    if (use_sub) {
        ushort4 s = *(const ushort4*)&subb[(size_t)n * KT + cb];
        r0 = alpha * a0 - bf2f(s.x);
        r1 = alpha * a1 - bf2f(s.y);
        r2 = alpha * a2 - bf2f(s.z);
        r3 = alpha * a3 - bf2f(s.w);
    } else {
        r0 = alpha * a0; r1 = alpha * a1; r2 = alpha * a2; r3 = alpha * a3;
    }
    ushort4 h;
    h.x = f2bf(r0); h.y = f2bf(r1); h.z = f2bf(r2); h.w = f2bf(r3);
    *(ushort4*)&outb[(size_t)n * KT + cb] = h;
}

// ---------------- fused bf16 MFMA GEMM (2-phase double-buffered) ----------------
// out[M=40000][256] = Abf[M][1280] @ WT^T + bias
// 64x128 tile, BK=64 -> 20 K-iters.
// T3-minimum 2-phase pipeline: stage tile k+1 into LDS buf^1 BEFORE computing
// tile k from buf, ONE __syncthreads per iter. The compiler's mandatory
// vmcnt(0)-drain before s_barrier then lands AFTER 12 ds_read + 16 MFMA of
// cover instead of immediately after issue (old version: 2 barriers, 0 cover).
// LDS 48 KB (2 x 24 KB): As [64r][8 granules], Bs [128r][8 granules], granule
// XOR-swizzle g^(row&7) -> wave64 ds_read_b128 uniformly 2-way (free per m136).
// __launch_bounds__(256,3) -> 3 blocks/CU (LDS-limited 160/48), 12 waves/CU.
__global__ __launch_bounds__(256, 3)
void gemm_mfma(const bf16_t* __restrict__ Abf,  // [NN][KT]
               const bf16_t* __restrict__ WT,   // [256][KT]
               const float* __restrict__ bias,
               float* __restrict__ out) {
    __shared__ bf16_t smem[2][12288];  // per buf: As = [0,4096), Bs = [4096,12288)
    int tid = threadIdx.x;
    int w = tid >> 6, lane = tid & 63;
    int m0 = blockIdx.x * 64;
    int n0 = blockIdx.y * 128;
    int wm = w & 1, wn = w >> 1;
    int quad = lane >> 4, l16 = lane & 15, l7 = l16 & 7;

    // staging: 1536 granules of 16B per K-iter; wave w call j covers
    // granules gi = (w*6+j)*64 + lane. gi<512 -> A slot, else B slot.
    const bf16_t* srcbase[6];
#pragma unroll
    for (int j = 0; j < 6; ++j) {
        int gi = (w * 6 + j) * 64 + lane;           // 0..1535
        int isB = gi >= 512;
        int t  = isB ? gi - 512 : gi;
        int row = t >> 3;                           // A: 0..63, B: 0..127
        int pg = t & 7;
        int g  = pg ^ (row & 7);                    // physical k-granule slot
        srcbase[j] = (isB ? WT + (size_t)(n0 + row) * KT
                          : Abf + (size_t)(m0 + row) * KT) + g * 8;
    }

    int arowb = wm * 32 + l16;    // A fragment base row (mt adds 16)
    int browb = wn * 64 + l16;    // B fragment base row (nt adds 16)

    floatx4 acc[2][4] = {};

    // prologue: stage tile 0 into buf 0 (compiler drains vmcnt before barrier)
#pragma unroll
    for (int j = 0; j < 6; ++j)
        GLL16(srcbase[j], &smem[0][(w * 6 + j) * 512]);
    __syncthreads();

    int cur = 0;
    for (int k0 = 0; k0 < KT; k0 += 64) {
        // issue NEXT tile's staging first -> latency hidden under compute below
        if (k0 + 64 < KT) {
#pragma unroll
            for (int j = 0; j < 6; ++j)
                GLL16(srcbase[j] + k0 + 64, &smem[cur ^ 1][(w * 6 + j) * 512]);
        }

        const bf16_t* sb = smem[cur];
#pragma unroll
        for (int c = 0; c < 2; ++c) {              // two 32-k chunks inside BK=64
            int gp   = (c * 4 + quad) ^ l7;        // physical granule for this frag
            int aoff = (arowb * 8 + gp) * 8;
            int boff = 4096 + (browb * 8 + gp) * 8;
            short8 af[2], bfr[4];
#pragma unroll
            for (int mt = 0; mt < 2; ++mt) af[mt]  = *(const short8*)&sb[aoff + mt * 1024];
#pragma unroll
            for (int nt = 0; nt < 4; ++nt) bfr[nt] = *(const short8*)&sb[boff + nt * 1024];
#pragma unroll
            for (int mt = 0; mt < 2; ++mt)
#pragma unroll
                for (int nt = 0; nt < 4; ++nt)
                    acc[mt][nt] = __builtin_amdgcn_mfma_f32_16x16x32_bf16(
                        af[mt], bfr[nt], acc[mt][nt], 0, 0, 0);
        }

        // single barrier per iter: (a) my ds_reads of buf[cur] are done before
        // anyone overwrites it next iter; (b) compiler's vmcnt(0) drain here
        // guarantees buf[cur^1]'s staged loads have landed for next iter.
        __syncthreads();
        cur ^= 1;
    }

    // epilogue: C/D layout col=lane&15, row=quad*4+reg  (m89-verified)
#pragma unroll
    for (int nt = 0; nt < 4; ++nt) {
        int n = n0 + wn * 64 + nt * 16 + l16;
        float bv = bias[n];
#pragma unroll
        for (int mt = 0; mt < 2; ++mt) {
            int mbase = m0 + wm * 32 + mt * 16 + quad * 4;
#pragma unroll
            for (int r = 0; r < 4; ++r)
                out[(size_t)(mbase + r) * C + n] = acc[mt][nt][r] + bv;
        }
    }
}

// ---------------- launch ----------------

extern "C" void kernel_launch(void* const* d_in, const int* in_sizes, int n_in,
                              void* d_out, int out_size, void* d_ws, size_t ws_size,
                              hipStream_t stream) {
    const float* x    = (const float*)d_in[0];
    const int*   ei   = (const int*)d_in[1];
    const float* ew   = (const float*)d_in[2];
    const float* W    = (const float*)d_in[3];   // [5][256][256]
    const float* bias = (const float*)d_in[4];
    float* out = (float*)d_out;

    char* p = (char*)d_ws;
    auto carve = [&](size_t bytes) {
        char* q = p;
        p += (bytes + 255) & ~(size_t)255;
        return q;
    };
    int*    deg     = (int*)   carve(NN * 4);
    int*    cnt     = (int*)   carve(NN * 4);
    int*    incl    = (int*)   carve(NN * 4);
    int*    bsum    = (int*)   carve(256 * 4);
    int*    row_ptr = (int*)   carve((NN + 1) * 4);
    int*    cursor  = (int*)   carve(NN * 4);
    int*    csr_col = (int*)   carve(NE * 4);
    float*  csr_val = (float*) carve(NE * 4);
    float*  dis     = (float*) carve(NN * 4);
    bf16_t* abf     = (bf16_t*)carve((size_t)NN * KT * 2);   // fused bf16 A (recursion state)
    bf16_t* WT      = (bf16_t*)carve((size_t)C * KT * 2);    // W transposed bf16
    (void)ws_size; (void)n_in; (void)in_sizes; (void)out_size;

    const int NB_E = (NE + 255) / 256;   // 1250
    const int NB_N = (NN + 255) / 256;   // 157

    hipMemsetAsync(deg, 0, NN * 4, stream);
    hipMemsetAsync(cnt, 0, NN * 4, stream);

    count_kernel<<<NB_E, 256, 0, stream>>>(ei, deg, cnt);
    dis_kernel<<<NB_N, 256, 0, stream>>>(deg, dis);
    scan1_kernel<<<NB_N, 256, 0, stream>>>(cnt, incl, bsum);
    scan2_kernel<<<1, 256, 0, stream>>>(bsum, NB_N);
    scan3_kernel<<<NB_N, 256, 0, stream>>>(cnt, incl, bsum, row_ptr, cursor);
    fill_kernel<<<NB_E, 256, 0, stream>>>(ei, ew, dis, cursor, csr_col, csr_val);

    convx_kernel<<<(NN * 64 + 255) / 256, 256, 0, stream>>>(x, abf);
    wt_kernel<<<(256 * KT + 255) / 256, 256, 0, stream>>>(W, WT);

    // Chebyshev recursion, bf16 state in abf chunks 0..4 (chunk k at abf + k*256)
    spmm_kernel<<<NN / 4, 256, 0, stream>>>(abf + 0 * 256, nullptr, row_ptr, csr_col,
                                            csr_val, abf + 1 * 256, 1.0f, 0);
    spmm_kernel<<<NN / 4, 256, 0, stream>>>(abf + 1 * 256, abf + 0 * 256, row_ptr,
                                            csr_col, csr_val, abf + 2 * 256, 2.0f, 1);
    spmm_kernel<<<NN / 4, 256, 0, stream>>>(abf + 2 * 256, abf + 1 * 256, row_ptr,
                                            csr_col, csr_val, abf + 3 * 256, 2.0f, 1);
    spmm_kernel<<<NN / 4, 256, 0, stream>>>(abf + 3 * 256, abf + 2 * 256, row_ptr,
                                            csr_col, csr_val, abf + 4 * 256, 2.0f, 1);

    // fused GEMM: out = abf @ WT^T + bias
    dim3 ggrid(625, 2);
    gemm_mfma<<<ggrid, 256, 0, stream>>>(abf, WT, bias, out);
}

// Round 2
// 305.777 us; speedup vs baseline: 1.0090x; 1.0090x over previous
//
#include <hip/hip_runtime.h>

#define NN 40000
#define NE 320000
#define C 256
#define KORD 5
#define KT 1280          // fused K = 5 * 256

typedef __attribute__((ext_vector_type(8))) short short8;   // 8 x bf16 (4 VGPR)
typedef __attribute__((ext_vector_type(4))) float floatx4;  // 4 x f32
typedef unsigned short bf16_t;

__device__ __forceinline__ bf16_t f2bf(float f) {
    union { float f; unsigned u; } v; v.f = f;
    unsigned r = v.u + 0x7fffu + ((v.u >> 16) & 1u);  // RTNE
    return (bf16_t)(r >> 16);
}
__device__ __forceinline__ float bf2f(bf16_t h) {
    union { unsigned u; float f; } v; v.u = ((unsigned)h) << 16;
    return v.f;
}

#define GLL16(gsrc, ldst)                                                        \
    __builtin_amdgcn_global_load_lds(                                            \
        (const __attribute__((address_space(1))) void*)(gsrc),                   \
        (__attribute__((address_space(3))) void*)(ldst), 16, 0, 0)

// ---------------- graph preprocessing ----------------

__global__ void count_kernel(const int* __restrict__ ei,
                             int* __restrict__ deg_keep,
                             int* __restrict__ cnt_all) {
    int e = blockIdx.x * 256 + threadIdx.x;
    if (e >= NE) return;
    int r = ei[e];
    int c = ei[NE + e];
    atomicAdd(&cnt_all[r], 1);
    if (r != c) atomicAdd(&deg_keep[r], 1);
}

__global__ void dis_kernel(const int* __restrict__ deg, float* __restrict__ dis) {
    int n = blockIdx.x * 256 + threadIdx.x;
    if (n >= NN) return;
    int d = deg[n];
    dis[n] = (d > 0) ? rsqrtf((float)d) : 0.0f;
}

__global__ void scan1_kernel(const int* __restrict__ cnt,
                             int* __restrict__ incl,
                             int* __restrict__ bsum) {
    __shared__ int s[256];
    int t = threadIdx.x;
    int idx = blockIdx.x * 256 + t;
    int v = (idx < NN) ? cnt[idx] : 0;
    s[t] = v;
    __syncthreads();
    for (int off = 1; off < 256; off <<= 1) {
        int add = (t >= off) ? s[t - off] : 0;
        __syncthreads();
        s[t] += add;
        __syncthreads();
    }
    if (idx < NN) incl[idx] = s[t];
    if (t == 255) bsum[blockIdx.x] = s[255];
}

__global__ void scan2_kernel(int* __restrict__ bsum, int nb) {
    __shared__ int s[256];
    int t = threadIdx.x;
    int v = (t < nb) ? bsum[t] : 0;
    s[t] = v;
    __syncthreads();
    for (int off = 1; off < 256; off <<= 1) {
        int add = (t >= off) ? s[t - off] : 0;
        __syncthreads();
        s[t] += add;
        __syncthreads();
    }
    if (t < nb) bsum[t] = s[t] - v;   // exclusive
}

__global__ void scan3_kernel(const int* __restrict__ cnt,
                             const int* __restrict__ incl,
                             const int* __restrict__ bexcl,
                             int* __restrict__ row_ptr,
                             int* __restrict__ cursor) {
    int idx = blockIdx.x * 256 + threadIdx.x;
    if (idx == 0) row_ptr[NN] = NE;
    if (idx >= NN) return;
    int rp = incl[idx] - cnt[idx] + bexcl[blockIdx.x];
    row_ptr[idx] = rp;
    cursor[idx]  = rp;
}

__global__ void fill_kernel(const int* __restrict__ ei,
                            const float* __restrict__ ew,
                            const float* __restrict__ dis,
                            int* __restrict__ cursor,
                            int* __restrict__ csr_col,
                            float* __restrict__ csr_val) {
    int e = blockIdx.x * 256 + threadIdx.x;
    if (e >= NE) return;
    int r = ei[e];
    int c = ei[NE + e];
    int pos = atomicAdd(&cursor[r], 1);
    float w = (r != c) ? ew[e] : 0.0f;     // removed self-loops -> weight 0
    csr_col[pos] = c;
    csr_val[pos] = -dis[r] * w * dis[c];
}

// convert x (fp32 [NN][256]) into bf16 A-chunk 0 of [NN][KT]
__global__ void convx_kernel(const float* __restrict__ x, bf16_t* __restrict__ abf) {
    int i = blockIdx.x * 256 + threadIdx.x;
    if (i >= NN * 64) return;
    int n = i >> 6, cg = i & 63;
    float4 f = *(const float4*)&x[(size_t)n * C + cg * 4];
    ushort4 h;
    h.x = f2bf(f.x); h.y = f2bf(f.y); h.z = f2bf(f.z); h.w = f2bf(f.w);
    *(ushort4*)&abf[(size_t)n * KT + cg * 4] = h;
}

// transpose+convert W[5][256][256] -> WT[n(256)][kt(1280)] bf16
__global__ void wt_kernel(const float* __restrict__ W, bf16_t* __restrict__ WT) {
    int t = blockIdx.x * 256 + threadIdx.x;
    if (t >= 256 * KT) return;
    int n = t & 255, kt = t >> 8;
    WT[(size_t)n * KT + kt] = f2bf(W[(size_t)kt * 256 + n]);
}

// ---------------- SpMM (bf16 state, unroll-8 MLP) ----------------
// outb[n][:] = bf16( alpha * sum_j val[j]*Vb[col[j]][:] - (use_sub ? subb[n][:] : 0) )
__global__ __launch_bounds__(256)
void spmm_kernel(const bf16_t* __restrict__ Vb,
                 const bf16_t* __restrict__ subb,
                 const int* __restrict__ row_ptr,
                 const int* __restrict__ csr_col,
                 const float* __restrict__ csr_val,
                 bf16_t* __restrict__ outb,
                 float alpha, int use_sub) {
    int wave = __builtin_amdgcn_readfirstlane(threadIdx.x >> 6);  // wave-uniform
    int lane = threadIdx.x & 63;
    int n = blockIdx.x * 4 + wave;          // grid is exactly NN/4 blocks
    int j0 = row_ptr[n];
    int j1 = row_ptr[n + 1];
    int cb = lane * 4;
    float a0 = 0.f, a1 = 0.f, a2 = 0.f, a3 = 0.f;
    int j = j0;
    for (; j + 8 <= j1; j += 8) {
        int cc[8]; float ww[8]; ushort4 vv[8];
#pragma unroll
        for (int u = 0; u < 8; ++u) { cc[u] = csr_col[j + u]; ww[u] = csr_val[j + u]; }
#pragma unroll
        for (int u = 0; u < 8; ++u) vv[u] = *(const ushort4*)&Vb[(size_t)cc[u] * KT + cb];
#pragma unroll
        for (int u = 0; u < 8; ++u) {
            a0 += ww[u] * bf2f(vv[u].x); a1 += ww[u] * bf2f(vv[u].y);
            a2 += ww[u] * bf2f(vv[u].z); a3 += ww[u] * bf2f(vv[u].w);
        }
    }
    for (; j + 4 <= j1; j += 4) {
        int cc[4]; float ww[4]; ushort4 vv[4];
#pragma unroll
        for (int u = 0; u < 4; ++u) { cc[u] = csr_col[j + u]; ww[u] = csr_val[j + u]; }
#pragma unroll
        for (int u = 0; u < 4; ++u) vv[u] = *(const ushort4*)&Vb[(size_t)cc[u] * KT + cb];
#pragma unroll
        for (int u = 0; u < 4; ++u) {
            a0 += ww[u] * bf2f(vv[u].x); a1 += ww[u] * bf2f(vv[u].y);
            a2 += ww[u] * bf2f(vv[u].z); a3 += ww[u] * bf2f(vv[u].w);
        }
    }
    for (; j < j1; ++j) {
        int   col = csr_col[j];
        float w   = csr_val[j];
        ushort4 v = *(const ushort4*)&Vb[(size_t)col * KT + cb];
        a0 += w * bf2f(v.x); a1 += w * bf2f(v.y);
        a2 += w * bf2f(v.z); a3 += w * bf2f(v.w);
    }
    float r0, r1, r2, r3;
    if (use_sub) {
        ushort4 s = *(const ushort4*)&subb[(size_t)n * KT + cb];
        r0 = alpha * a0 - bf2f(s.x);
        r1 = alpha * a1 - bf2f(s.y);
        r2 = alpha * a2 - bf2f(s.z);
        r3 = alpha * a3 - bf2f(s.w);
    } else {
        r0 = alpha * a0; r1 = alpha * a1; r2 = alpha * a2; r3 = alpha * a3;
    }
    ushort4 h;
    h.x = f2bf(r0); h.y = f2bf(r1); h.z = f2bf(r2); h.w = f2bf(r3);
    *(ushort4*)&outb[(size_t)n * KT + cb] = h;
}

// ---------------- fused bf16 MFMA GEMM (3-buffer, counted-vmcnt pipeline) ----------------
// out[M=40000][256] = Abf[M][1280] @ WT^T + bias
// 64x128 tile, BK=64 -> 20 K-iters (NT=20).
// T3+T4: prefetch depth 2. Tile t's 6 loads/wave issued at iter t-2, waited at
// iter t with s_waitcnt vmcnt(6) (in-order retirement: oldest 6 = tile t) then
// RAW s_barrier -- no compiler vmcnt(0) drain, so tile t+1/t+2 loads stay in
// flight across the barrier (~2 compute phases ~ HBM latency of cover).
// Iter order: wait(t) -> barrier -> issue(t+2 into buf[(t+2)%3]) -> compute(t).
// Safety: buf[(t+2)%3]=buf[(t-1)%3] was last read in iter t-1's compute, which
// precedes this barrier for every wave.  All branches wave/block-uniform.
// LDS 72 KB (3 x 24 KB) -> 2 blocks/CU. Granule XOR-swizzle g^(row&7) ->
// wave64 ds_read_b128 uniformly 2-way (free per m136).
__global__ __launch_bounds__(256, 2)
void gemm_mfma(const bf16_t* __restrict__ Abf,  // [NN][KT]
               const bf16_t* __restrict__ WT,   // [256][KT]
               const float* __restrict__ bias,
               float* __restrict__ out) {
    __shared__ bf16_t smem[3][12288];  // per buf: As = [0,4096), Bs = [4096,12288)
    int tid = threadIdx.x;
    int w = tid >> 6, lane = tid & 63;
    int m0 = blockIdx.x * 64;
    int n0 = blockIdx.y * 128;
    int wm = w & 1, wn = w >> 1;
    int quad = lane >> 4, l16 = lane & 15, l7 = l16 & 7;

    // staging: 1536 granules of 16B per K-iter; wave w call j covers
    // granules gi = (w*6+j)*64 + lane. gi<512 -> A slot, else B slot.
    const bf16_t* srcbase[6];
#pragma unroll
    for (int j = 0; j < 6; ++j) {
        int gi = (w * 6 + j) * 64 + lane;           // 0..1535
        int isB = gi >= 512;
        int t  = isB ? gi - 512 : gi;
        int row = t >> 3;                           // A: 0..63, B: 0..127
        int pg = t & 7;
        int g  = pg ^ (row & 7);                    // physical k-granule slot
        srcbase[j] = (isB ? WT + (size_t)(n0 + row) * KT
                          : Abf + (size_t)(m0 + row) * KT) + g * 8;
    }

    int arowb = wm * 32 + l16;    // A fragment base row (mt adds 16)
    int browb = wn * 64 + l16;    // B fragment base row (nt adds 16)

    floatx4 acc[2][4] = {};

    const int NT = KT / 64;       // 20

    // prologue: issue tiles 0 and 1 (12 loads/wave outstanding)
#pragma unroll
    for (int j = 0; j < 6; ++j)
        GLL16(srcbase[j] + 0 * 64, &smem[0][(w * 6 + j) * 512]);
#pragma unroll
    for (int j = 0; j < 6; ++j)
        GLL16(srcbase[j] + 1 * 64, &smem[1][(w * 6 + j) * 512]);

    int bufc = 0;                 // buffer holding tile t
    for (int t = 0; t < NT; ++t) {
        // wait: tile t's 6 loads (oldest outstanding) have landed in LDS
        if (t < NT - 1) {
            asm volatile("s_waitcnt vmcnt(6)" ::: "memory");
        } else {
            asm volatile("s_waitcnt vmcnt(0)" ::: "memory");
        }
        __builtin_amdgcn_sched_barrier(0);
        __builtin_amdgcn_s_barrier();   // all waves: tile t landed; buf[(t-1)%3] reads done

        // issue tile t+2 into buf[(t+2)%3] (== buf[(t-1)%3], safe after barrier)
        if (t + 2 < NT) {
            int bnext = bufc + 2; if (bnext >= 3) bnext -= 3;
#pragma unroll
            for (int j = 0; j < 6; ++j)
                GLL16(srcbase[j] + (t + 2) * 64, &smem[bnext][(w * 6 + j) * 512]);
        }

        const bf16_t* sb = smem[bufc];
#pragma unroll
        for (int c = 0; c < 2; ++c) {              // two 32-k chunks inside BK=64
            int gp   = (c * 4 + quad) ^ l7;        // physical granule for this frag
            int aoff = (arowb * 8 + gp) * 8;
            int boff = 4096 + (browb * 8 + gp) * 8;
            short8 af[2], bfr[4];
#pragma unroll
            for (int mt = 0; mt < 2; ++mt) af[mt]  = *(const short8*)&sb[aoff + mt * 1024];
#pragma unroll
            for (int nt = 0; nt < 4; ++nt) bfr[nt] = *(const short8*)&sb[boff + nt * 1024];
#pragma unroll
            for (int mt = 0; mt < 2; ++mt)
#pragma unroll
                for (int nt = 0; nt < 4; ++nt)
                    acc[mt][nt] = __builtin_amdgcn_mfma_f32_16x16x32_bf16(
                        af[mt], bfr[nt], acc[mt][nt], 0, 0, 0);
        }

        bufc += 1; if (bufc == 3) bufc = 0;
    }

    // epilogue: C/D layout col=lane&15, row=quad*4+reg  (m89-verified)
#pragma unroll
    for (int nt = 0; nt < 4; ++nt) {
        int n = n0 + wn * 64 + nt * 16 + l16;
        float bv = bias[n];
#pragma unroll
        for (int mt = 0; mt < 2; ++mt) {
            int mbase = m0 + wm * 32 + mt * 16 + quad * 4;
#pragma unroll
            for (int r = 0; r < 4; ++r)
                out[(size_t)(mbase + r) * C + n] = acc[mt][nt][r] + bv;
        }
    }
}

// ---------------- launch ----------------

extern "C" void kernel_launch(void* const* d_in, const int* in_sizes, int n_in,
                              void* d_out, int out_size, void* d_ws, size_t ws_size,
                              hipStream_t stream) {
    const float* x    = (const float*)d_in[0];
    const int*   ei   = (const int*)d_in[1];
    const float* ew   = (const float*)d_in[2];
    const float* W    = (const float*)d_in[3];   // [5][256][256]
    const float* bias = (const float*)d_in[4];
    float* out = (float*)d_out;

    char* p = (char*)d_ws;
    auto carve = [&](size_t bytes) {
        char* q = p;
        p += (bytes + 255) & ~(size_t)255;
        return q;
    };
    int*    deg     = (int*)   carve(NN * 4);
    int*    cnt     = (int*)   carve(NN * 4);
    int*    incl    = (int*)   carve(NN * 4);
    int*    bsum    = (int*)   carve(256 * 4);
    int*    row_ptr = (int*)   carve((NN + 1) * 4);
    int*    cursor  = (int*)   carve(NN * 4);
    int*    csr_col = (int*)   carve(NE * 4);
    float*  csr_val = (float*) carve(NE * 4);
    float*  dis     = (float*) carve(NN * 4);
    bf16_t* abf     = (bf16_t*)carve((size_t)NN * KT * 2);   // fused bf16 A (recursion state)
    bf16_t* WT      = (bf16_t*)carve((size_t)C * KT * 2);    // W transposed bf16
    (void)ws_size; (void)n_in; (void)in_sizes; (void)out_size;

    const int NB_E = (NE + 255) / 256;   // 1250
    const int NB_N = (NN + 255) / 256;   // 157

    hipMemsetAsync(deg, 0, NN * 4, stream);
    hipMemsetAsync(cnt, 0, NN * 4, stream);

    count_kernel<<<NB_E, 256, 0, stream>>>(ei, deg, cnt);
    dis_kernel<<<NB_N, 256, 0, stream>>>(deg, dis);
    scan1_kernel<<<NB_N, 256, 0, stream>>>(cnt, incl, bsum);
    scan2_kernel<<<1, 256, 0, stream>>>(bsum, NB_N);
    scan3_kernel<<<NB_N, 256, 0, stream>>>(cnt, incl, bsum, row_ptr, cursor);
    fill_kernel<<<NB_E, 256, 0, stream>>>(ei, ew, dis, cursor, csr_col, csr_val);

    convx_kernel<<<(NN * 64 + 255) / 256, 256, 0, stream>>>(x, abf);
    wt_kernel<<<(256 * KT + 255) / 256, 256, 0, stream>>>(W, WT);

    // Chebyshev recursion, bf16 state in abf chunks 0..4 (chunk k at abf + k*256)
    spmm_kernel<<<NN / 4, 256, 0, stream>>>(abf + 0 * 256, nullptr, row_ptr, csr_col,
                                            csr_val, abf + 1 * 256, 1.0f, 0);
    spmm_kernel<<<NN / 4, 256, 0, stream>>>(abf + 1 * 256, abf + 0 * 256, row_ptr,
                                            csr_col, csr_val, abf + 2 * 256, 2.0f, 1);
    spmm_kernel<<<NN / 4, 256, 0, stream>>>(abf + 2 * 256, abf + 1 * 256, row_ptr,
                                            csr_col, csr_val, abf + 3 * 256, 2.0f, 1);
    spmm_kernel<<<NN / 4, 256, 0, stream>>>(abf + 3 * 256, abf + 2 * 256, row_ptr,
                                            csr_col, csr_val, abf + 4 * 256, 2.0f, 1);

    // fused GEMM: out = abf @ WT^T + bias
    dim3 ggrid(625, 2);
    gemm_mfma<<<ggrid, 256, 0, stream>>>(abf, WT, bias, out);
}